// Round 2
// baseline (490.197 us; speedup 1.0000x reference)
//
#include <hip/hip_runtime.h>
#include <cmath>

#define NHEADS 32
#define DIM 128
#define SPLITS 8
#define KSPLIT 8
#define QKV_N 4352
#define HID 4096

__device__ __forceinline__ float wred_max(float x) {
#pragma unroll
  for (int o = 32; o > 0; o >>= 1) x = fmaxf(x, __shfl_xor(x, o));
  return x;
}
__device__ __forceinline__ float wred_sum(float x) {
#pragma unroll
  for (int o = 32; o > 0; o >>= 1) x += __shfl_xor(x, o);
  return x;
}

// C[64,N] += A[64,K] @ W[K,N], split-K partials. grid=(N/64, KSPLIT), block=256
__global__ __launch_bounds__(256) void gemm64_part(
    const float* __restrict__ A, const float* __restrict__ W,
    float* __restrict__ P, int N, int K)
{
  __shared__ float As[32][64];   // As[k][m] (transposed)
  __shared__ float Ws[32][68];   // Ws[k][n], padded
  const int t = threadIdx.x;
  const int n0 = blockIdx.x * 64;
  const int KS = K / KSPLIT;
  const int kbase = blockIdx.y * KS;
  const int tx = t & 15, ty = t >> 4;
  float acc[4][4] = {{0.f, 0.f, 0.f, 0.f}, {0.f, 0.f, 0.f, 0.f},
                     {0.f, 0.f, 0.f, 0.f}, {0.f, 0.f, 0.f, 0.f}};
  for (int kc = 0; kc < KS; kc += 32) {
    {
      int idx = t;
#pragma unroll
      for (int it = 0; it < 2; ++it, idx += 256) {
        const int m = idx >> 3, kq = idx & 7;
        const float4 av = *(const float4*)(A + (size_t)m * K + kbase + kc + kq * 4);
        As[kq * 4 + 0][m] = av.x; As[kq * 4 + 1][m] = av.y;
        As[kq * 4 + 2][m] = av.z; As[kq * 4 + 3][m] = av.w;
      }
      idx = t;
#pragma unroll
      for (int it = 0; it < 2; ++it, idx += 256) {
        const int kk = idx >> 4, nq = idx & 15;
        const float4 wv = *(const float4*)(W + (size_t)(kbase + kc + kk) * N + n0 + nq * 4);
        *(float4*)&Ws[kk][nq * 4] = wv;
      }
    }
    __syncthreads();
#pragma unroll 8
    for (int kk = 0; kk < 32; ++kk) {
      const float4 a = *(const float4*)&As[kk][ty * 4];
      const float4 w = *(const float4*)&Ws[kk][tx * 4];
      acc[0][0] += a.x * w.x; acc[0][1] += a.x * w.y; acc[0][2] += a.x * w.z; acc[0][3] += a.x * w.w;
      acc[1][0] += a.y * w.x; acc[1][1] += a.y * w.y; acc[1][2] += a.y * w.z; acc[1][3] += a.y * w.w;
      acc[2][0] += a.z * w.x; acc[2][1] += a.z * w.y; acc[2][2] += a.z * w.z; acc[2][3] += a.z * w.w;
      acc[3][0] += a.w * w.x; acc[3][1] += a.w * w.y; acc[3][2] += a.w * w.z; acc[3][3] += a.w * w.w;
    }
    __syncthreads();
  }
  float* base = P + (size_t)blockIdx.y * 64 * N + (size_t)(ty * 4) * N + n0 + tx * 4;
#pragma unroll
  for (int i = 0; i < 4; ++i) {
    const float4 v = make_float4(acc[i][0], acc[i][1], acc[i][2], acc[i][3]);
    *(float4*)(base + (size_t)i * N) = v;
  }
}

__global__ __launch_bounds__(256) void reduce_parts(
    const float* __restrict__ P, float* __restrict__ C, int total)
{
  const int i = (blockIdx.x * 256 + threadIdx.x) * 4;
  if (i >= total) return;
  float4 s = *(const float4*)(P + i);
#pragma unroll
  for (int k = 1; k < KSPLIT; ++k) {
    const float4 v = *(const float4*)(P + (size_t)k * total + i);
    s.x += v.x; s.y += v.y; s.z += v.z; s.w += v.w;
  }
  *(float4*)(C + i) = s;
}

// RoPE in place on q (32 heads) and k row of qkv. grid=64, block=256
__global__ __launch_bounds__(256) void rope_kernel(
    float* __restrict__ qkv, const int* __restrict__ positions)
{
  const int b = blockIdx.x;
  float* row = qkv + (size_t)b * QKV_N;
  const float pos = (float)positions[b];
  for (int it = threadIdx.x; it < 33 * 64; it += 256) {
    const int r = it >> 6, i = it & 63;
    float* x = row + (r < 32 ? r * DIM : HID);
    const float ex = (float)(2 * i) * (1.0f / 128.0f);
    const float inv = 1.0f / powf(10000.0f, ex);
    const float ang = pos * inv;
    const float c = cosf(ang), sn = sinf(ang);
    const float x1 = x[i], x2 = x[i + 64];
    x[i]      = x1 * c - x2 * sn;
    x[i + 64] = x2 * c + x1 * sn;
  }
}

// Flash-decoding attention. grid=(64, SPLITS), block=256 (4 waves x 8 heads; lane = position)
__global__ __launch_bounds__(256) void attn_kernel(
    const float* __restrict__ qkv,
    const float* __restrict__ k_cache, const float* __restrict__ v_cache,
    const int* __restrict__ block_tables, const int* __restrict__ context_lens,
    float* __restrict__ pm, float* __restrict__ pl, float* __restrict__ pacc)
{
  const int b = blockIdx.x, s = blockIdx.y;
  const int t = threadIdx.x;
  const int w = t >> 6, lane = t & 63;
  const int ctx = context_lens[b];
  const int pos = ctx - 1;
  const int chunk = (ctx + SPLITS - 1) / SPLITS;
  const int start = s * chunk;
  const int end = min(start + chunk, ctx);

  __shared__ float qs[NHEADS][DIM];       // 16 KB
  __shared__ float Ks[64][DIM + 4];       // 33 KB, padded
  __shared__ const float* vrow[64];

  const float* qbase = qkv + (size_t)b * QKV_N;
#pragma unroll
  for (int i = 0; i < 4; ++i) {
    const int idx = t + i * 256;
    ((float4*)qs)[idx] = ((const float4*)qbase)[idx];
  }

  const int h0 = w * 8;
  const float scale = 0.08838834764831845f;  // 1/sqrt(128)
  float mh[8], lh[8], a0[8], a1[8];
#pragma unroll
  for (int h = 0; h < 8; ++h) { mh[h] = -1e30f; lh[h] = 0.f; a0[h] = 0.f; a1[h] = 0.f; }

  for (int t0 = start; t0 < end; t0 += 64) {
    const int nv = min(64, end - t0);
    __syncthreads();   // protect Ks/vrow from previous iteration's readers (and qs on iter 0)
    {
      const int rr = t >> 5;   // 0..7
      const int c = t & 31;    // 0..31 (float4 column)
      for (int rb = 0; rb < 64; rb += 8) {
        const int row = rb + rr;
        if (row < nv) {
          const int gpos = t0 + row;
          const int blk = block_tables[b * 256 + (gpos >> 4)];
          const float* kp;
          const float* vp;
          if (gpos == pos) {
            kp = qbase + HID;           // freshly RoPE'd k
            vp = qbase + HID + DIM;     // fresh v
          } else {
            const size_t cidx = ((size_t)blk * 16 + (gpos & 15)) * DIM;
            kp = k_cache + cidx;
            vp = v_cache + cidx;
          }
          if (c == 0) vrow[row] = vp;
          const float4 kv = ((const float4*)kp)[c];
          *(float4*)&Ks[row][c * 4] = kv;
        }
      }
    }
    __syncthreads();

    // scores: lane = position, 8 heads per wave
    float sc[8] = {0.f, 0.f, 0.f, 0.f, 0.f, 0.f, 0.f, 0.f};
#pragma unroll 4
    for (int kk = 0; kk < 32; ++kk) {
      const float4 kv = *(const float4*)&Ks[lane][kk * 4];
#pragma unroll
      for (int h = 0; h < 8; ++h) {
        const float4 qv = *(const float4*)&qs[h0 + h][kk * 4];
        sc[h] += qv.x * kv.x + qv.y * kv.y + qv.z * kv.z + qv.w * kv.w;
      }
    }
    float p[8];
#pragma unroll
    for (int h = 0; h < 8; ++h) {
      const float sv = (lane < nv) ? sc[h] * scale : -1e30f;
      const float tm = wred_max(sv);
      const float nm = fmaxf(mh[h], tm);
      const float corr = expf(mh[h] - nm);
      p[h] = expf(sv - nm);   // masked lanes: exp(-huge) == 0
      lh[h] = lh[h] * corr + wred_sum(p[h]);
      a0[h] *= corr; a1[h] *= corr;
      mh[h] = nm;
    }
    // PV: V straight from global (L2-hot), p broadcast via shfl
    for (int l = 0; l < nv; ++l) {
      const float* vp = vrow[l];
      const float v0 = vp[lane];
      const float v1 = vp[64 + lane];
#pragma unroll
      for (int h = 0; h < 8; ++h) {
        const float pb = __shfl(p[h], l);
        a0[h] += pb * v0;
        a1[h] += pb * v1;
      }
    }
  }

  const size_t base = ((size_t)(b * SPLITS + s) * NHEADS + h0);
#pragma unroll
  for (int h = 0; h < 8; ++h) {
    if (lane == 0) { pm[base + h] = mh[h]; pl[base + h] = lh[h]; }
    pacc[(base + h) * DIM + lane] = a0[h];
    pacc[(base + h) * DIM + 64 + lane] = a1[h];
  }
}

// combine partials -> attn[b][h*128+d]. grid=2048, block=128
__global__ __launch_bounds__(128) void combine_kernel(
    const float* __restrict__ pm, const float* __restrict__ pl,
    const float* __restrict__ pacc, float* __restrict__ attn)
{
  const int bh = blockIdx.x;
  const int b = bh >> 5, h = bh & 31;
  const int d = threadIdx.x;
  float ms[SPLITS], ls[SPLITS];
  float M = -1e30f;
#pragma unroll
  for (int s = 0; s < SPLITS; ++s) {
    ms[s] = pm[(size_t)(b * SPLITS + s) * NHEADS + h];
    ls[s] = pl[(size_t)(b * SPLITS + s) * NHEADS + h];
    M = fmaxf(M, ms[s]);
  }
  float L = 0.f, o = 0.f;
#pragma unroll
  for (int s = 0; s < SPLITS; ++s) {
    const float wgt = expf(ms[s] - M);
    L += ls[s] * wgt;
    o += wgt * pacc[((size_t)(b * SPLITS + s) * NHEADS + h) * DIM + d];
  }
  attn[(size_t)b * HID + h * DIM + d] = o / L;
}

extern "C" void kernel_launch(void* const* d_in, const int* in_sizes, int n_in,
                              void* d_out, int out_size, void* d_ws, size_t ws_size,
                              hipStream_t stream) {
  const float* hidden   = (const float*)d_in[0];
  const float* wqkv     = (const float*)d_in[1];
  const float* wdense   = (const float*)d_in[2];
  const float* k_cache  = (const float*)d_in[3];
  const float* v_cache  = (const float*)d_in[4];
  const int* positions    = (const int*)d_in[5];   // integer inputs arrive as int32
  const int* block_tables = (const int*)d_in[6];
  const int* context_lens = (const int*)d_in[7];
  float* out = (float*)d_out;

  float* qkv  = (float*)d_ws;                 // 64*4352
  float* attn = qkv + 64 * QKV_N;             // 64*4096
  float* gp   = attn + 64 * HID;              // KSPLIT*64*4352 (max)
  float* pm   = gp + (size_t)KSPLIT * 64 * QKV_N;   // 64*SPLITS*32
  float* pl   = pm + 64 * SPLITS * NHEADS;
  float* pacc = pl + 64 * SPLITS * NHEADS;    // 64*SPLITS*32*128

  // 1) qkv = hidden @ wqkv
  gemm64_part<<<dim3(QKV_N / 64, KSPLIT), 256, 0, stream>>>(hidden, wqkv, gp, QKV_N, HID);
  reduce_parts<<<(64 * QKV_N) / 1024, 256, 0, stream>>>(gp, qkv, 64 * QKV_N);
  // 2) RoPE on q and k
  rope_kernel<<<64, 256, 0, stream>>>(qkv, positions);
  // 3) attention (flash-decoding, SPLITS context chunks)
  attn_kernel<<<dim3(64, SPLITS), 256, 0, stream>>>(qkv, k_cache, v_cache,
                                                    block_tables, context_lens, pm, pl, pacc);
  combine_kernel<<<64 * NHEADS, 128, 0, stream>>>(pm, pl, pacc, attn);
  // 4) out = attn @ wdense
  gemm64_part<<<dim3(HID / 64, KSPLIT), 256, 0, stream>>>(attn, wdense, gp, HID, HID);
  reduce_parts<<<(64 * HID) / 1024, 256, 0, stream>>>(gp, out, 64 * HID);
}